// Round 2
// baseline (46.497 us; speedup 1.0000x reference)
//
#include <hip/hip_runtime.h>

// out[t] = x[t], except out[t] = 0 when x[t] > 0.5 and (t - lastzero(t)) is even,
// where lastzero(t) = most recent index < t with x <= 0.5 (or -1).
// Derivation: b[t] = (out[t] > thr) obeys b[t] = c[t] && !b[t-1]  (c[t] = x[t] > thr),
// which alternates within runs of c=1 -> parity of distance to last c=0.
//
// NOTE: every __shfl_* is executed UNCONDITIONALLY by all 64 lanes.
// ds_bpermute is convergent; putting it under a divergent branch (ternary arm)
// makes reads from masked-off source lanes undefined.

constexpr int S = 8192;
constexpr int TPB = 1024;
constexpr int EPT = S / TPB;  // 8 elements per thread (2 x float4)
constexpr float THR = 0.5f;

__global__ __launch_bounds__(TPB) void notwo_kernel(const float* __restrict__ x,
                                                    float* __restrict__ out) {
    const int row = blockIdx.x;
    const int tid = threadIdx.x;
    const size_t rowoff = (size_t)row * S;

    const float4* xv = reinterpret_cast<const float4*>(x + rowoff) + tid * 2;
    float4 v0 = xv[0];
    float4 v1 = xv[1];
    float f[EPT] = {v0.x, v0.y, v0.z, v0.w, v1.x, v1.y, v1.z, v1.w};

    const int base = tid * EPT;

    // Local last-zero index within this thread's chunk (-1 if none).
    int lastz = -1;
    #pragma unroll
    for (int k = 0; k < EPT; ++k) {
        if (!(f[k] > THR)) lastz = base + k;
    }

    // Block-wide exclusive max-scan of lastz (identity -1).
    const int lane = tid & 63;
    const int wv = tid >> 6;  // wave id, 0..15
    int incl = lastz;
    #pragma unroll
    for (int off = 1; off < 64; off <<= 1) {
        // All lanes shuffle; lanes < off receive their own value (clamp),
        // so the max is a no-op for them. No divergent guard around bpermute.
        int up = __shfl_up(incl, off, 64);
        incl = max(incl, up);
    }
    __shared__ int wtot[TPB / 64];
    if (lane == 63) wtot[wv] = incl;
    __syncthreads();
    int prefix = -1;
    #pragma unroll
    for (int w = 0; w < TPB / 64; ++w) {
        int t = wtot[w];
        if (w < wv) prefix = max(prefix, t);
    }
    // Exclusive value: shuffle executed by ALL lanes, then a plain select.
    int up1 = __shfl_up(incl, 1, 64);
    int excl = (lane == 0) ? -1 : up1;
    int carry = max(prefix, excl);  // last zero index strictly before this chunk

    // Walk own 8 elements with the carry.
    #pragma unroll
    for (int k = 0; k < EPT; ++k) {
        const int t = base + k;
        const bool c = f[k] > THR;
        if (c && (((t - carry) & 1) == 0)) f[k] = 0.0f;
        if (!c) carry = t;
    }

    float4* ov = reinterpret_cast<float4*>(out + rowoff) + tid * 2;
    ov[0] = make_float4(f[0], f[1], f[2], f[3]);
    ov[1] = make_float4(f[4], f[5], f[6], f[7]);
}

extern "C" void kernel_launch(void* const* d_in, const int* in_sizes, int n_in,
                              void* d_out, int out_size, void* d_ws, size_t ws_size,
                              hipStream_t stream) {
    const float* x = (const float*)d_in[0];
    float* out = (float*)d_out;
    const int B = out_size / S;  // 4096 rows
    notwo_kernel<<<B, TPB, 0, stream>>>(x, out);
}